// Round 16
// baseline (68.511 us; speedup 1.0000x reference)
//
#include <hip/hip_runtime.h>

constexpr int D = 20;

typedef float f4 __attribute__((ext_vector_type(4)));
typedef unsigned int u32;

__device__ __forceinline__ u32 bf16_rne(float f) {
    u32 u = __float_as_uint(f);
    return (u + 0x7FFFu + ((u >> 16) & 1u)) >> 16;
}

__device__ __forceinline__ u32 combo_idx(const f4* __restrict__ xr, float tv) {
    f4 a = xr[0], b = xr[1], c = xr[2], d = xr[3], e = xr[4];
    u32 id = (tv != 0.0f) ? (1u << 20) : 0u;
    id |= ((u32)a.x) << 19; id |= ((u32)a.y) << 18;
    id |= ((u32)a.z) << 17; id |= ((u32)a.w) << 16;
    id |= ((u32)b.x) << 15; id |= ((u32)b.y) << 14;
    id |= ((u32)b.z) << 13; id |= ((u32)b.w) << 12;
    id |= ((u32)c.x) << 11; id |= ((u32)c.y) << 10;
    id |= ((u32)c.z) << 9;  id |= ((u32)c.w) << 8;
    id |= ((u32)d.x) << 7;  id |= ((u32)d.y) << 6;
    id |= ((u32)d.z) << 5;  id |= ((u32)d.w) << 4;
    id |= ((u32)e.x) << 3;  id |= ((u32)e.y) << 2;
    id |= ((u32)e.z) << 1;  id |= ((u32)e.w);
    return id;
}

// ---------------------------------------------------------------------------
// Kernel A: build the bf16-packed table (REGULAR stores -> lands in L2/L3 and
// stays resident) + all pure-fill outputs with NONTEMPORAL stores (the 185 MB
// fill stream must not sweep the freshly built table out of L3 before B runs).
// ---------------------------------------------------------------------------
__global__ __launch_bounds__(256) void cevae_A_build_fill(
    const f4* __restrict__ qw, const f4* __restrict__ qb,
    uint4* __restrict__ tab, int nq,              // nq = nc/4
    const float* __restrict__ dx_w, const float* __restrict__ dx_b,
    const float* __restrict__ sc_tw, const float* __restrict__ sc_tb,
    float* __restrict__ out, int n_rows,
    int n_build_blocks, int n_fill_blocks)
{
    int bid = blockIdx.x;
    if (bid < n_build_blocks) {
        // ---- table build: coalesced, 16.8 MB read + 8.4 MB write (cached) ----
        int i = bid * 256 + threadIdx.x;
        if (i >= nq) return;
        f4 w = qw[i];
        f4 b = qb[i];
        uint4 o;
        o.x = (bf16_rne(w.x) << 16) | bf16_rne(b.x);
        o.y = (bf16_rne(w.y) << 16) | bf16_rne(b.y);
        o.z = (bf16_rne(w.z) << 16) | bf16_rne(b.z);
        o.w = (bf16_rne(w.w) << 16) | bf16_rne(b.w);
        tab[i] = o;
    } else {
        // ---- pure fill: x_logits0/1 + t_logits0/1 splats (NT stores) ----
        int fb = bid - n_build_blocks;
        unsigned Q = (unsigned)n_rows * D / 4;      // f4 per region (5M)
        f4* r0 = (f4*)(out + n_rows);               // x_logits0
        f4* r1 = r0 + Q;                            // x_logits1
        unsigned stride = (unsigned)n_fill_blocks * 256;
        unsigned q0 = (unsigned)fb * 256 + threadIdx.x;
        for (unsigned q = q0; q < Q; q += stride) {
            int cb = (int)(q % 5u) * 4;             // column base 0,4,8,12,16
            float b0 = dx_b[cb + 0], b1 = dx_b[cb + 1];
            float b2 = dx_b[cb + 2], b3 = dx_b[cb + 3];
            float w0 = dx_w[cb + 0], w1 = dx_w[cb + 1];
            float w2 = dx_w[cb + 2], w3 = dx_w[cb + 3];
            f4 v0 = {b0, b1, b2, b3};
            f4 v1 = {w0 + b0, w1 + b1, w2 + b2, w3 + b3};
            __builtin_nontemporal_store(v0, r0 + q);
            __builtin_nontemporal_store(v1, r1 + q);
        }
        // constant heads: t_logits0 = tb, t_logits1 = tw + tb
        float tw = *sc_tw, tb = *sc_tb;
        f4 s0 = {tb, tb, tb, tb};
        float t1v = tw + tb;
        f4 s1 = {t1v, t1v, t1v, t1v};
        size_t o3 = (size_t)n_rows * (size_t)(1 + 2 * D);
        unsigned Qt = (unsigned)n_rows / 4;         // 250K f4 per region
        f4* h0 = (f4*)(out + o3);
        f4* h1 = (f4*)(out + o3 + (size_t)n_rows);
        for (unsigned q = q0; q < Qt; q += stride) {
            __builtin_nontemporal_store(s0, h0 + q);
            __builtin_nontemporal_store(s1, h1 + q);
        }
    }
}

// ---------------------------------------------------------------------------
// Kernel B: rows job with 4-way MLP. Each thread owns 4 rows from 4
// quarter-offset streams (all loads/stores lane-consecutive per stream);
// idx computed sequentially (bounded VGPR), then 4 independent random 4B
// gathers issued together -> 4 gather round-trips overlap. Working set
// ~96 MB streams + 8.4 MB L3-resident table -> gathers are cache hits.
// ---------------------------------------------------------------------------
template <bool USE_TAB>
__global__ __launch_bounds__(256) void cevae_B_rows4(
    const float* __restrict__ x, const float* __restrict__ t,
    const float* __restrict__ y, const u32* __restrict__ tab,
    const float* __restrict__ qz_w, const float* __restrict__ qz_b,
    const float* __restrict__ sc_y0w, const float* __restrict__ sc_y0b,
    const float* __restrict__ sc_y1w, const float* __restrict__ sc_y1b,
    const float* __restrict__ pz, float* __restrict__ out, int n_rows)
{
    int Qr = n_rows >> 2;                      // 250,000 rows per stream
    int m = blockIdx.x * 256 + threadIdx.x;
    if (m >= Qr) return;

    int n0 = m, n1 = m + Qr, n2 = m + 2 * Qr, n3 = m + 3 * Qr;

    float t0 = t[n0], t1 = t[n1], t2 = t[n2], t3 = t[n3];
    u32 i0 = combo_idx((const f4*)(x + (size_t)n0 * D), t0);
    u32 i1 = combo_idx((const f4*)(x + (size_t)n1 * D), t1);
    u32 i2 = combo_idx((const f4*)(x + (size_t)n2 * D), t2);
    u32 i3 = combo_idx((const f4*)(x + (size_t)n3 * D), t3);

    float y0v = y[n0], y1v = y[n1], y2v = y[n2], y3v = y[n3];

    float z0, z1, z2, z3;
    if (USE_TAB) {
        // 4 independent random 4B gathers in flight
        u32 g0 = tab[i0], g1 = tab[i1], g2 = tab[i2], g3 = tab[i3];
        z0 = fmaf(__uint_as_float(g0 & 0xFFFF0000u), y0v, __uint_as_float(g0 << 16));
        z1 = fmaf(__uint_as_float(g1 & 0xFFFF0000u), y1v, __uint_as_float(g1 << 16));
        z2 = fmaf(__uint_as_float(g2 & 0xFFFF0000u), y2v, __uint_as_float(g2 << 16));
        z3 = fmaf(__uint_as_float(g3 & 0xFFFF0000u), y3v, __uint_as_float(g3 << 16));
    } else {
        z0 = fmaf(qz_w[i0], y0v, qz_b[i0]);
        z1 = fmaf(qz_w[i1], y1v, qz_b[i1]);
        z2 = fmaf(qz_w[i2], y2v, qz_b[i2]);
        z3 = fmaf(qz_w[i3], y3v, qz_b[i3]);
    }
    __builtin_nontemporal_store(z0, out + n0);
    __builtin_nontemporal_store(z1, out + n1);
    __builtin_nontemporal_store(z2, out + n2);
    __builtin_nontemporal_store(z3, out + n3);

    float y0w = *sc_y0w, y0b = *sc_y0b;
    float y1w = *sc_y1w, y1b = *sc_y1b;
    float dy0 = y1b - y0b;
    float dy1 = (y1w + y1b) - (y0w + y0b), c1 = y0w + y0b;

    // layout: [z(N)][xl0(N*D)][xl1(N*D)][t0(N)][t1(N)][y0(N)][y1(N)][pz(1)]
    size_t o3 = (size_t)n_rows * (size_t)(1 + 2 * D);
    float* yl0 = out + o3 + 2 * (size_t)n_rows;
    float* yl1 = out + o3 + 3 * (size_t)n_rows;
    __builtin_nontemporal_store(fmaf(t0, dy0, y0b), yl0 + n0);
    __builtin_nontemporal_store(fmaf(t1, dy0, y0b), yl0 + n1);
    __builtin_nontemporal_store(fmaf(t2, dy0, y0b), yl0 + n2);
    __builtin_nontemporal_store(fmaf(t3, dy0, y0b), yl0 + n3);
    __builtin_nontemporal_store(fmaf(t0, dy1, c1), yl1 + n0);
    __builtin_nontemporal_store(fmaf(t1, dy1, c1), yl1 + n1);
    __builtin_nontemporal_store(fmaf(t2, dy1, c1), yl1 + n2);
    __builtin_nontemporal_store(fmaf(t3, dy1, c1), yl1 + n3);
    if (m == 0) out[o3 + 4 * (size_t)n_rows] = pz[0];
}

extern "C" void kernel_launch(void* const* d_in, const int* in_sizes, int n_in,
                              void* d_out, int out_size, void* d_ws, size_t ws_size,
                              hipStream_t stream) {
    const float* x    = (const float*)d_in[0];
    const float* t    = (const float*)d_in[1];
    const float* y    = (const float*)d_in[2];
    const float* qz_w = (const float*)d_in[3];
    const float* qz_b = (const float*)d_in[4];
    const float* dx_w = (const float*)d_in[5];
    const float* dx_b = (const float*)d_in[6];
    const float* t_w  = (const float*)d_in[7];
    const float* t_b  = (const float*)d_in[8];
    const float* y0_w = (const float*)d_in[9];
    const float* y0_b = (const float*)d_in[10];
    const float* y1_w = (const float*)d_in[11];
    const float* y1_b = (const float*)d_in[12];
    const float* pz   = (const float*)d_in[13];
    float* out = (float*)d_out;

    int n_rows = in_sizes[0] / D;            // 1,000,000
    int nc     = in_sizes[3];                // 2^21
    int Qr     = n_rows / 4;                 // 250,000
    int n_b_blocks = (Qr + 255) / 256;       // 977
    n_b_blocks = ((n_b_blocks + 7) / 8) * 8; // 984

    size_t tab_bytes = (size_t)nc * sizeof(u32);   // 8.4 MB
    if (ws_size >= tab_bytes) {
        uint4* tab = (uint4*)d_ws;
        int nq = nc / 4;                           // 524,288
        int n_build_blocks = (nq + 255) / 256;     // 2048
        int n_fill_blocks  = 4096;
        cevae_A_build_fill<<<n_build_blocks + n_fill_blocks, 256, 0, stream>>>(
            (const f4*)qz_w, (const f4*)qz_b, tab, nq,
            dx_w, dx_b, t_w, t_b, out, n_rows, n_build_blocks, n_fill_blocks);
        cevae_B_rows4<true><<<n_b_blocks, 256, 0, stream>>>(
            x, t, y, (const u32*)tab, qz_w, qz_b,
            y0_w, y0_b, y1_w, y1_b, pz, out, n_rows);
    } else {
        cevae_A_build_fill<<<4096, 256, 0, stream>>>(
            (const f4*)qz_w, (const f4*)qz_b, nullptr, 0,
            dx_w, dx_b, t_w, t_b, out, n_rows, 0, 4096);
        cevae_B_rows4<false><<<n_b_blocks, 256, 0, stream>>>(
            x, t, y, nullptr, qz_w, qz_b,
            y0_w, y0_b, y1_w, y1_b, pz, out, n_rows);
    }
}

// Round 17
// 65.344 us; speedup vs baseline: 1.0485x; 1.0485x over previous
//
#include <hip/hip_runtime.h>

constexpr int D = 20;

typedef float f4 __attribute__((ext_vector_type(4)));
typedef unsigned int u32;

__device__ __forceinline__ u32 bf16_rne(float f) {
    u32 u = __float_as_uint(f);
    return (u + 0x7FFFu + ((u >> 16) & 1u)) >> 16;
}

// ---------------------------------------------------------------------------
// K1: pack (qz_w, qz_b) as bf16 pair into one uint32 per entry (8.4 MB).
// ---------------------------------------------------------------------------
__global__ __launch_bounds__(256) void cevae_build_tab(
    const f4* __restrict__ qw, const f4* __restrict__ qb,
    uint4* __restrict__ tab, int nq)   // nq = nc/4
{
    int i = blockIdx.x * 256 + threadIdx.x;
    if (i >= nq) return;
    f4 w = qw[i];
    f4 b = qb[i];
    uint4 o;
    o.x = (bf16_rne(w.x) << 16) | bf16_rne(b.x);
    o.y = (bf16_rne(w.y) << 16) | bf16_rne(b.y);
    o.z = (bf16_rne(w.z) << 16) | bf16_rne(b.z);
    o.w = (bf16_rne(w.w) << 16) | bf16_rne(b.w);
    tab[i] = o;
}

// ---------------------------------------------------------------------------
// K2: r13's uniform fused kernel with ONE change: x is loaded wave-
// cooperatively (lane-consecutive f4s, 16 lines/instruction instead of ~64)
// and the 21-bit combo index is assembled in LDS via atomicOr (each lane
// contributes the 4-bit nibble of the f4 it loaded; lds_idx seeded with the
// row's t-bit). Everything else (fill, heads, gather, nt stores) identical.
// ---------------------------------------------------------------------------
template <bool USE_TAB>
__global__ __launch_bounds__(256) void cevae_fused13_kernel(
    const float* __restrict__ x, const float* __restrict__ t,
    const float* __restrict__ y, const u32* __restrict__ tab,
    const float* __restrict__ qz_w, const float* __restrict__ qz_b,
    const float* __restrict__ dx_w, const float* __restrict__ dx_b,
    const float* __restrict__ sc_tw, const float* __restrict__ sc_tb,
    const float* __restrict__ sc_y0w, const float* __restrict__ sc_y0b,
    const float* __restrict__ sc_y1w, const float* __restrict__ sc_y1b,
    const float* __restrict__ pz, float* __restrict__ out, int n_rows)
{
    __shared__ u32 lidx[4][64];

    int tid = threadIdx.x;
    int n = blockIdx.x * 256 + tid;
    size_t o3 = (size_t)n_rows * (size_t)(1 + 2 * D);
    bool live = (n < n_rows);

    float tv = 0.0f, yv = 0.0f;
    unsigned idx = 0;

    // block-uniform fast/slow split so barriers are safe
    bool fast_block = ((blockIdx.x + 1) * 256 <= n_rows);
    if (fast_block) {
        int wid = tid >> 6;                     // wave id in block
        int j   = tid & 63;                     // lane
        int wb  = blockIdx.x * 256 + wid * 64;  // first row of this wave

        tv = t[n];
        yv = y[n];
        // seed with this row's t-bit
        lidx[wid][j] = (tv != 0.0f) ? (1u << 20) : 0u;
        __syncthreads();

        // wave-cooperative coalesced load of 64 rows (320 f4s), nibble-OR
        const f4* xw = (const f4*)x + (size_t)wb * 5;
#pragma unroll
        for (int k = 0; k < 5; ++k) {
            int q = j + 64 * k;                 // f4 index within wave span
            f4 v = xw[q];
            int r = q / 5;                      // row within wave
            int c = q - 5 * r;                  // f4-column 0..4
            u32 nib = (((u32)v.x) << 3) | (((u32)v.y) << 2) |
                      (((u32)v.z) << 1) | ((u32)v.w);
            atomicOr(&lidx[wid][r], nib << (16 - 4 * c));
        }
        __syncthreads();
        idx = lidx[wid][j];
    } else if (live) {
        // tail: scalar path (r13)
        const f4* xr = (const f4*)(x + (size_t)n * D);
        f4 a = xr[0], b = xr[1], c = xr[2], d = xr[3], e = xr[4];
        tv = t[n];
        yv = y[n];
        idx = (tv != 0.0f) ? (1u << 20) : 0u;
        idx |= ((u32)a.x) << 19; idx |= ((u32)a.y) << 18;
        idx |= ((u32)a.z) << 17; idx |= ((u32)a.w) << 16;
        idx |= ((u32)b.x) << 15; idx |= ((u32)b.y) << 14;
        idx |= ((u32)b.z) << 13; idx |= ((u32)b.w) << 12;
        idx |= ((u32)c.x) << 11; idx |= ((u32)c.y) << 10;
        idx |= ((u32)c.z) << 9;  idx |= ((u32)c.w) << 8;
        idx |= ((u32)d.x) << 7;  idx |= ((u32)d.y) << 6;
        idx |= ((u32)d.z) << 5;  idx |= ((u32)d.w) << 4;
        idx |= ((u32)e.x) << 3;  idx |= ((u32)e.y) << 2;
        idx |= ((u32)e.z) << 1;  idx |= ((u32)e.w);
    }

    // ---- issue gather (in flight across the fill burst) ----
    u32 g = 0;
    float gw = 0.0f, gb = 0.0f;
    if (live) {
        if (USE_TAB) {
            g = tab[idx];
        } else {
            gw = qz_w[idx];
            gb = qz_b[idx];
        }
    }

    // ---- fill part: flat coalesced nt f4 stores (r13 verbatim) ----
    {
        unsigned stride = (unsigned)gridDim.x * 256u;
        unsigned Q = (unsigned)n_rows * D / 4;      // f4 per region (5M)
        f4* r0 = (f4*)(out + n_rows);               // x_logits0
        f4* r1 = r0 + Q;                            // x_logits1
        unsigned q0 = (unsigned)blockIdx.x * 256u + tid;
        for (unsigned q = q0; q < Q; q += stride) {
            int cb = (int)(q % 5u) * 4;             // column base 0,4,8,12,16
            float b0 = dx_b[cb + 0], b1 = dx_b[cb + 1];
            float b2 = dx_b[cb + 2], b3 = dx_b[cb + 3];
            float w0 = dx_w[cb + 0], w1 = dx_w[cb + 1];
            float w2 = dx_w[cb + 2], w3 = dx_w[cb + 3];
            f4 v0 = {b0, b1, b2, b3};
            f4 v1 = {w0 + b0, w1 + b1, w2 + b2, w3 + b3};
            __builtin_nontemporal_store(v0, r0 + q);
            __builtin_nontemporal_store(v1, r1 + q);
        }
        // constant heads: t_logits0 = tb, t_logits1 = tw + tb
        float tw = *sc_tw, tb = *sc_tb;
        f4 s0 = {tb, tb, tb, tb};
        float t1v = tw + tb;
        f4 s1 = {t1v, t1v, t1v, t1v};
        unsigned Qt = (unsigned)n_rows / 4;         // 250K f4 per region
        f4* h0 = (f4*)(out + o3);
        f4* h1 = (f4*)(out + o3 + (size_t)n_rows);
        for (unsigned q = q0; q < Qt; q += stride) {
            __builtin_nontemporal_store(s0, h0 + q);
            __builtin_nontemporal_store(s1, h1 + q);
        }
    }

    // ---- consume gather + per-row outputs ----
    if (live) {
        float y0w = *sc_y0w, y0b = *sc_y0b;
        float y1w = *sc_y1w, y1b = *sc_y1b;
        __builtin_nontemporal_store(fmaf(tv, y1b - y0b, y0b),
                                    out + o3 + 2 * (size_t)n_rows + n);
        __builtin_nontemporal_store(fmaf(tv, (y1w + y1b) - (y0w + y0b), y0w + y0b),
                                    out + o3 + 3 * (size_t)n_rows + n);
        float z;
        if (USE_TAB) {
            z = fmaf(__uint_as_float(g & 0xFFFF0000u), yv,
                     __uint_as_float(g << 16));
        } else {
            z = fmaf(gw, yv, gb);
        }
        __builtin_nontemporal_store(z, out + n);
        if (n == 0) out[o3 + 4 * (size_t)n_rows] = pz[0];
    }
}

extern "C" void kernel_launch(void* const* d_in, const int* in_sizes, int n_in,
                              void* d_out, int out_size, void* d_ws, size_t ws_size,
                              hipStream_t stream) {
    const float* x    = (const float*)d_in[0];
    const float* t    = (const float*)d_in[1];
    const float* y    = (const float*)d_in[2];
    const float* qz_w = (const float*)d_in[3];
    const float* qz_b = (const float*)d_in[4];
    const float* dx_w = (const float*)d_in[5];
    const float* dx_b = (const float*)d_in[6];
    const float* t_w  = (const float*)d_in[7];
    const float* t_b  = (const float*)d_in[8];
    const float* y0_w = (const float*)d_in[9];
    const float* y0_b = (const float*)d_in[10];
    const float* y1_w = (const float*)d_in[11];
    const float* y1_b = (const float*)d_in[12];
    const float* pz   = (const float*)d_in[13];
    float* out = (float*)d_out;

    int n_rows = in_sizes[0] / D;            // 1,000,000
    int nc     = in_sizes[3];                // 2^21
    int n_blocks = (n_rows + 255) / 256;     // 3907
    n_blocks = ((n_blocks + 7) / 8) * 8;     // 3912, even XCD spread

    size_t tab_bytes = (size_t)nc * sizeof(u32);   // 8.4 MB
    if (ws_size >= tab_bytes) {
        uint4* tab = (uint4*)d_ws;
        int nq = nc / 4;                     // 524,288
        cevae_build_tab<<<(nq + 255) / 256, 256, 0, stream>>>(
            (const f4*)qz_w, (const f4*)qz_b, tab, nq);
        cevae_fused13_kernel<true><<<n_blocks, 256, 0, stream>>>(
            x, t, y, (const u32*)tab, qz_w, qz_b, dx_w, dx_b, t_w, t_b,
            y0_w, y0_b, y1_w, y1_b, pz, out, n_rows);
    } else {
        cevae_fused13_kernel<false><<<n_blocks, 256, 0, stream>>>(
            x, t, y, nullptr, qz_w, qz_b, dx_w, dx_b, t_w, t_b,
            y0_w, y0_b, y1_w, y1_b, pz, out, n_rows);
    }
}